// Round 4
// baseline (593.538 us; speedup 1.0000x reference)
//
#include <hip/hip_runtime.h>
#include <math.h>

#define N_NODES 8192
#define NFEAT 256
#define NHID 64
#define NHEADS 4
#define NCLASS 121
#define NCPAD 128
#define CAP 256
#define LRALPHA 0.2f

#define GEMM_BLOCKS 128          // 8192/64 row tiles, all 4 heads fused
#define CSR_BASE    GEMM_BLOCKS  // csr rows occupy [128, 128+8192)
#define PAD_BLOCK   (CSR_BASE + N_NODES)

// ---------------------------------------------------------------------------
// K_A: fused independent front-end.
//  blocks [0,128):          gemm1 (head-fused) + fs1/fd1 butterfly epilogue
//  blocks [128,128+8192):   build_csr row = b-128
//  block  PAD_BLOCK:        pad W_out->Wpad, a_out->apad
// gemm blocks dispatch FIRST so their ~20us compute hides under the
// 8192 HBM-bound csr blocks (~45-50us). LDS capped at 34KB -> 4 blocks/CU.
// ---------------------------------------------------------------------------
__global__ __launch_bounds__(256) void fused_A(const float* __restrict__ adj,
                                               const float* __restrict__ x,
                                               const float* __restrict__ Ws,
                                               const float* __restrict__ a_heads,
                                               const float* __restrict__ Wout,
                                               const float* __restrict__ aout,
                                               int* __restrict__ nbr,
                                               int* __restrict__ deg,
                                               float* __restrict__ Wh1,
                                               float* __restrict__ fs1,
                                               float* __restrict__ fd1,
                                               float* __restrict__ Wpad,
                                               float* __restrict__ apad) {
    __shared__ __align__(16) char smem[64 * 132 * 4];  // 33.8 KB
    int b = blockIdx.x;
    int tid = threadIdx.x;

    if (b >= CSR_BASE && b < PAD_BLOCK) {
        // ---------------- build_csr ----------------
        int row = b - CSR_BASE;
        int* cnt = (int*)smem;
        if (tid == 0) *cnt = 0;
        __syncthreads();
        const float4* arow = (const float4*)(adj + (size_t)row * N_NODES);
        for (int j4 = tid; j4 < N_NODES / 4; j4 += 256) {
            float4 v = arow[j4];
            if (v.x > 0.f) { int s = atomicAdd(cnt, 1); if (s < CAP) nbr[row * CAP + s] = j4 * 4 + 0; }
            if (v.y > 0.f) { int s = atomicAdd(cnt, 1); if (s < CAP) nbr[row * CAP + s] = j4 * 4 + 1; }
            if (v.z > 0.f) { int s = atomicAdd(cnt, 1); if (s < CAP) nbr[row * CAP + s] = j4 * 4 + 2; }
            if (v.w > 0.f) { int s = atomicAdd(cnt, 1); if (s < CAP) nbr[row * CAP + s] = j4 * 4 + 3; }
        }
        __syncthreads();
        if (tid == 0) deg[row] = *cnt < CAP ? *cnt : CAP;
        return;
    }
    if (b == PAD_BLOCK) {
        // ---------------- pad params ----------------
        for (int idx = tid; idx < 256 * NCPAD; idx += 256) {
            int k = idx >> 7, c = idx & 127;
            Wpad[idx] = (c < NCLASS) ? Wout[k * NCLASS + c] : 0.f;
        }
        if (tid < 256) {
            int c = tid & 127;
            float v = 0.f;
            if (c < NCLASS) v = (tid < 128) ? aout[c] : aout[NCLASS + c];
            apad[tid] = v;
        }
        return;
    }

    // ---------------- gemm1, 4 heads fused, + coef1 epilogue ----------------
    float (*xs)[132] = (float(*)[132])smem;
    int r0 = b * 64;
    int d = tid & 63;                 // hidden dim = lane
    int rb = (tid >> 6) * 16;         // 16 rows per thread
    float acc[NHEADS][16];
#pragma unroll
    for (int h = 0; h < NHEADS; h++)
#pragma unroll
        for (int r = 0; r < 16; r++) acc[h][r] = 0.f;

    const float* Wd = Ws + d;         // Ws[h][k][d]
    for (int ph = 0; ph < 2; ph++) {
        for (int t = tid; t < 64 * 32; t += 256) {
            int r = t >> 5, c4 = t & 31;
            *(float4*)&xs[r][c4 * 4] =
                *(const float4*)(x + (size_t)(r0 + r) * NFEAT + ph * 128 + c4 * 4);
        }
        __syncthreads();
        for (int k4 = 0; k4 < 128; k4 += 4) {
            int kg = ph * 128 + k4;
            float bb[NHEADS][4];
#pragma unroll
            for (int h = 0; h < NHEADS; h++)
#pragma unroll
                for (int kk = 0; kk < 4; kk++)
                    bb[h][kk] = Wd[(size_t)h * NFEAT * NHID + (kg + kk) * NHID];
#pragma unroll
            for (int r = 0; r < 16; r++) {
                float4 a = *(const float4*)&xs[rb + r][k4];
#pragma unroll
                for (int h = 0; h < NHEADS; h++)
                    acc[h][r] += a.x * bb[h][0] + a.y * bb[h][1] +
                                 a.z * bb[h][2] + a.w * bb[h][3];
            }
        }
        __syncthreads();
    }
    // store Wh1 (layout [i][h*64+d])
#pragma unroll
    for (int h = 0; h < NHEADS; h++)
#pragma unroll
        for (int r = 0; r < 16; r++)
            Wh1[(size_t)(r0 + rb + r) * 256 + h * NHID + d] = acc[h][r];
    // coef1: fs1[h][i] = Wh[i][h][:].a_src, fd1 likewise — butterfly over lanes
    float asrc[NHEADS], adst[NHEADS];
#pragma unroll
    for (int h = 0; h < NHEADS; h++) {
        asrc[h] = a_heads[h * 2 * NHID + d];
        adst[h] = a_heads[h * 2 * NHID + NHID + d];
    }
#pragma unroll
    for (int h = 0; h < NHEADS; h++) {
#pragma unroll
        for (int r = 0; r < 16; r++) {
            float s = acc[h][r] * asrc[h];
            float dd = acc[h][r] * adst[h];
#pragma unroll
            for (int o = 32; o > 0; o >>= 1) { s += __shfl_xor(s, o); dd += __shfl_xor(dd, o); }
            if (d == 0) {
                fs1[h * N_NODES + r0 + rb + r] = s;
                fd1[h * N_NODES + r0 + rb + r] = dd;
            }
        }
    }
}

// ---------------------------------------------------------------------------
// K_B: layer-1 sparse softmax + aggregate + ELU (unchanged from R3).
// ---------------------------------------------------------------------------
__global__ __launch_bounds__(256) void attn_agg1(const int* __restrict__ nbr,
                                                 const int* __restrict__ deg,
                                                 const float* __restrict__ Wh1,
                                                 const float* __restrict__ fs1,
                                                 const float* __restrict__ fd1,
                                                 float* __restrict__ hcat) {
    int i = blockIdx.x;
    int h = threadIdx.x >> 6, lane = threadIdx.x & 63;
    __shared__ float ebuf[NHEADS][CAP + 1];
    __shared__ int nbrs[CAP];
    __shared__ float inv_s[NHEADS];
    __shared__ float part[NHEADS][256];
    int dg = deg[i];
    for (int t = threadIdx.x; t < dg; t += 256) nbrs[t] = nbr[i * CAP + t];
    __syncthreads();
    float fsi = fs1[h * N_NODES + i];
    const float* fdh = fd1 + h * N_NODES;
    float m = -3.4e38f;
    for (int t = lane; t < dg; t += 64) {
        float e = fsi + fdh[nbrs[t]];
        e = e > 0.f ? e : LRALPHA * e;
        ebuf[h][t] = e;
        m = fmaxf(m, e);
    }
#pragma unroll
    for (int o = 32; o > 0; o >>= 1) m = fmaxf(m, __shfl_xor(m, o));
    float s = 0.f;
    for (int t = lane; t < dg; t += 64) {
        float p = __expf(ebuf[h][t] - m);
        ebuf[h][t] = p;
        s += p;
    }
#pragma unroll
    for (int o = 32; o > 0; o >>= 1) s += __shfl_xor(s, o);
    if (lane == 0) inv_s[h] = 1.f / s;
    __syncthreads();
    int w = h;
    int hh = lane >> 4;
    float4 acc = make_float4(0.f, 0.f, 0.f, 0.f);
    int t = w;
    for (; t + 8 <= dg; t += 8) {
        int j0 = nbrs[t], j1 = nbrs[t + 4];
        float4 v0 = ((const float4*)(Wh1 + (size_t)j0 * 256))[lane];
        float4 v1 = ((const float4*)(Wh1 + (size_t)j1 * 256))[lane];
        float p0 = ebuf[hh][t], p1 = ebuf[hh][t + 4];
        acc.x += p0 * v0.x; acc.y += p0 * v0.y; acc.z += p0 * v0.z; acc.w += p0 * v0.w;
        acc.x += p1 * v1.x; acc.y += p1 * v1.y; acc.z += p1 * v1.z; acc.w += p1 * v1.w;
    }
    for (; t < dg; t += 4) {
        int j = nbrs[t];
        float4 v = ((const float4*)(Wh1 + (size_t)j * 256))[lane];
        float p = ebuf[hh][t];
        acc.x += p * v.x; acc.y += p * v.y; acc.z += p * v.z; acc.w += p * v.w;
    }
    ((float4*)part[w])[lane] = acc;
    __syncthreads();
    int dim = threadIdx.x;
    float r = part[0][dim] + part[1][dim] + part[2][dim] + part[3][dim];
    r *= inv_s[dim >> 6];
    r = r > 0.f ? r : expm1f(r);
    hcat[(size_t)i * 256 + dim] = r;
}

// ---------------------------------------------------------------------------
// K_C: layer-2 GEMM + coef2 butterfly epilogue.
// ---------------------------------------------------------------------------
__global__ __launch_bounds__(256) void gemm2(const float* __restrict__ hcat,
                                             const float* __restrict__ Wpad,
                                             const float* __restrict__ apad,
                                             float* __restrict__ Wh2,
                                             float* __restrict__ fs2,
                                             float* __restrict__ fd2) {
    int r0 = blockIdx.x * 64;
    __shared__ float xs[64][260];
    for (int t = threadIdx.x; t < 64 * 64; t += 256) {
        int r = t >> 6, c4 = t & 63;
        *(float4*)&xs[r][c4 * 4] = *(const float4*)(hcat + (size_t)(r0 + r) * 256 + c4 * 4);
    }
    __syncthreads();
    int lane = threadIdx.x & 63;
    int c0 = lane * 2;
    int rb = (threadIdx.x >> 6) * 16;
    float acc0[16] = {}, acc1[16] = {};
    for (int k4 = 0; k4 < 256; k4 += 4) {
        float2 b0 = *(const float2*)&Wpad[(k4 + 0) * NCPAD + c0];
        float2 b1 = *(const float2*)&Wpad[(k4 + 1) * NCPAD + c0];
        float2 b2 = *(const float2*)&Wpad[(k4 + 2) * NCPAD + c0];
        float2 b3 = *(const float2*)&Wpad[(k4 + 3) * NCPAD + c0];
#pragma unroll
        for (int r = 0; r < 16; r++) {
            float4 a = *(const float4*)&xs[rb + r][k4];
            acc0[r] += a.x * b0.x + a.y * b1.x + a.z * b2.x + a.w * b3.x;
            acc1[r] += a.x * b0.y + a.y * b1.y + a.z * b2.y + a.w * b3.y;
        }
    }
#pragma unroll
    for (int r = 0; r < 16; r++)
        *(float2*)&Wh2[(size_t)(r0 + rb + r) * NCPAD + c0] = make_float2(acc0[r], acc1[r]);
    // coef2: fs2[i] = Wh2[i][:].apad[0:128], fd2[i] = Wh2[i][:].apad[128:256]
    float as0 = apad[c0], as1 = apad[c0 + 1];
    float ad0 = apad[128 + c0], ad1 = apad[128 + c0 + 1];
#pragma unroll
    for (int r = 0; r < 16; r++) {
        float s = acc0[r] * as0 + acc1[r] * as1;
        float dd = acc0[r] * ad0 + acc1[r] * ad1;
#pragma unroll
        for (int o = 32; o > 0; o >>= 1) { s += __shfl_xor(s, o); dd += __shfl_xor(dd, o); }
        if (lane == 0) { fs2[r0 + rb + r] = s; fd2[r0 + rb + r] = dd; }
    }
}

// ---------------------------------------------------------------------------
// K_D: layer-2 sparse softmax + aggregate (unchanged from R3; 256 threads).
// ---------------------------------------------------------------------------
__global__ __launch_bounds__(256) void attn_agg2(const int* __restrict__ nbr,
                                                 const int* __restrict__ deg,
                                                 const float* __restrict__ Wh2,
                                                 const float* __restrict__ fs2,
                                                 const float* __restrict__ fd2,
                                                 float* __restrict__ out) {
    int i = blockIdx.x;
    int w = threadIdx.x >> 6, lane = threadIdx.x & 63;
    __shared__ float ebuf[CAP];
    __shared__ int nbrs[CAP];
    __shared__ float red[4];
    __shared__ float part[4][128];
    __shared__ float inv_s;
    int dg = deg[i];
    for (int t = threadIdx.x; t < dg; t += 256) nbrs[t] = nbr[i * CAP + t];
    __syncthreads();
    float fsi = fs2[i];
    float m = -3.4e38f;
    for (int t = threadIdx.x; t < dg; t += 256) {
        float e = fsi + fd2[nbrs[t]];
        e = e > 0.f ? e : LRALPHA * e;
        ebuf[t] = e;
        m = fmaxf(m, e);
    }
#pragma unroll
    for (int o = 32; o > 0; o >>= 1) m = fmaxf(m, __shfl_xor(m, o));
    if (lane == 0) red[w] = m;
    __syncthreads();
    m = fmaxf(fmaxf(red[0], red[1]), fmaxf(red[2], red[3]));
    float s = 0.f;
    for (int t = threadIdx.x; t < dg; t += 256) {
        float p = __expf(ebuf[t] - m);
        ebuf[t] = p;
        s += p;
    }
#pragma unroll
    for (int o = 32; o > 0; o >>= 1) s += __shfl_xor(s, o);
    __syncthreads();
    if (lane == 0) red[w] = s;
    __syncthreads();
    if (threadIdx.x == 0) inv_s = 1.f / (red[0] + red[1] + red[2] + red[3]);
    __syncthreads();
    float2 acc = make_float2(0.f, 0.f);
    int t = w;
    for (; t + 8 <= dg; t += 8) {
        int j0 = nbrs[t], j1 = nbrs[t + 4];
        float2 v0 = ((const float2*)(Wh2 + (size_t)j0 * NCPAD))[lane];
        float2 v1 = ((const float2*)(Wh2 + (size_t)j1 * NCPAD))[lane];
        float p0 = ebuf[t], p1 = ebuf[t + 4];
        acc.x += p0 * v0.x; acc.y += p0 * v0.y;
        acc.x += p1 * v1.x; acc.y += p1 * v1.y;
    }
    for (; t < dg; t += 4) {
        int j = nbrs[t];
        float2 v = ((const float2*)(Wh2 + (size_t)j * NCPAD))[lane];
        float p = ebuf[t];
        acc.x += p * v.x; acc.y += p * v.y;
    }
    ((float2*)part[w])[lane] = acc;
    __syncthreads();
    if (threadIdx.x < NCPAD) {
        int dim = threadIdx.x;
        float r = (part[0][dim] + part[1][dim] + part[2][dim] + part[3][dim]) * inv_s;
        if (dim < NCLASS) out[(size_t)i * NCLASS + dim] = r;
    }
}

// ---------------------------------------------------------------------------

extern "C" void kernel_launch(void* const* d_in, const int* in_sizes, int n_in,
                              void* d_out, int out_size, void* d_ws, size_t ws_size,
                              hipStream_t stream) {
    const float* x       = (const float*)d_in[0];  // [8192,256]
    const float* adj     = (const float*)d_in[1];  // [8192,8192]
    const float* Ws      = (const float*)d_in[2];  // [4,256,64]
    const float* a_heads = (const float*)d_in[3];  // [4,128]
    const float* Wout    = (const float*)d_in[4];  // [256,121]
    const float* aout    = (const float*)d_in[5];  // [242]
    float* out = (float*)d_out;                    // [8192,121]

    char* ws = (char*)d_ws;
    size_t off = 0;
    auto alloc = [&](size_t bytes) { void* p = ws + off; off = (off + bytes + 255) & ~(size_t)255; return p; };
    int*   nbr  = (int*)  alloc((size_t)N_NODES * CAP * 4);
    int*   deg  = (int*)  alloc((size_t)N_NODES * 4);
    float* Wh1  = (float*)alloc((size_t)N_NODES * NHEADS * NHID * 4);
    float* fs1  = (float*)alloc((size_t)NHEADS * N_NODES * 4);
    float* fd1  = (float*)alloc((size_t)NHEADS * N_NODES * 4);
    float* hcat = (float*)alloc((size_t)N_NODES * NHEADS * NHID * 4);
    float* Wh2  = (float*)alloc((size_t)N_NODES * NCPAD * 4);
    float* fs2  = (float*)alloc((size_t)N_NODES * 4);
    float* fd2  = (float*)alloc((size_t)N_NODES * 4);
    float* Wpad = (float*)alloc((size_t)256 * NCPAD * 4);
    float* apad = (float*)alloc((size_t)256 * 4);

    fused_A<<<PAD_BLOCK + 1, 256, 0, stream>>>(adj, x, Ws, a_heads, Wout, aout,
                                               nbr, deg, Wh1, fs1, fd1, Wpad, apad);
    attn_agg1<<<N_NODES, 256, 0, stream>>>(nbr, deg, Wh1, fs1, fd1, hcat);
    gemm2<<<N_NODES / 64, 256, 0, stream>>>(hcat, Wpad, apad, Wh2, fs2, fd2);
    attn_agg2<<<N_NODES, 256, 0, stream>>>(nbr, deg, Wh2, fs2, fd2, out);
}

// Round 5
// 560.326 us; speedup vs baseline: 1.0593x; 1.0593x over previous
//
#include <hip/hip_runtime.h>
#include <math.h>

#define N_NODES 8192
#define NFEAT 256
#define NHID 64
#define NHEADS 4
#define NCLASS 121
#define NCPAD 128
#define CAP 256
#define LRALPHA 0.2f

// ---------------------------------------------------------------------------
// K1: build_csr — one block per row, minimal LDS (max occupancy).
// All 8 float4 loads preloaded per thread (8 independent VMEM in flight/wave),
// then ballot-compaction: one LDS atomic per wave-step (lane 0) instead of
// per-edge atomics. Neighbor order is scrambled vs sequential — harmless
// (softmax/aggregate order-invariant to fp rounding).
// ---------------------------------------------------------------------------
__global__ __launch_bounds__(256) void build_csr(const float* __restrict__ adj,
                                                 int* __restrict__ nbr,
                                                 int* __restrict__ deg) {
    int row = blockIdx.x;
    int tid = threadIdx.x;
    int lane = tid & 63;
    __shared__ int cnt;
    if (tid == 0) cnt = 0;
    __syncthreads();
    const float4* arow = (const float4*)(adj + (size_t)row * N_NODES);
    float4 v[8];
#pragma unroll
    for (int it = 0; it < 8; it++) v[it] = arow[tid + it * 256];
#pragma unroll
    for (int it = 0; it < 8; it++) {
        int jb = (tid + it * 256) * 4;
#pragma unroll
        for (int c = 0; c < 4; c++) {
            float val = (c == 0) ? v[it].x : (c == 1) ? v[it].y : (c == 2) ? v[it].z : v[it].w;
            bool p = val > 0.f;
            unsigned long long mk = __ballot(p);
            int nset = __popcll(mk);
            int wbase = 0;
            if (lane == 0 && nset) wbase = atomicAdd(&cnt, nset);
            wbase = __shfl(wbase, 0);
            if (p) {
                int pos = wbase + __popcll(mk & ((1ull << lane) - 1ull));
                if (pos < CAP) nbr[row * CAP + pos] = jb + c;
            }
        }
    }
    __syncthreads();
    if (tid == 0) deg[row] = cnt < CAP ? cnt : CAP;
}

// ---------------------------------------------------------------------------
// K2: gemm1, 4 heads fused, + coef1 butterfly epilogue. Standalone (its LDS
// no longer throttles csr). Block 128 does the param padding instead.
// ---------------------------------------------------------------------------
__global__ __launch_bounds__(256) void gemm1(const float* __restrict__ x,
                                             const float* __restrict__ Ws,
                                             const float* __restrict__ a_heads,
                                             const float* __restrict__ Wout,
                                             const float* __restrict__ aout,
                                             float* __restrict__ Wh1,
                                             float* __restrict__ fs1,
                                             float* __restrict__ fd1,
                                             float* __restrict__ Wpad,
                                             float* __restrict__ apad) {
    int b = blockIdx.x;
    int tid = threadIdx.x;
    if (b == N_NODES / 64) {
        // ---------------- pad params ----------------
        for (int idx = tid; idx < 256 * NCPAD; idx += 256) {
            int k = idx >> 7, c = idx & 127;
            Wpad[idx] = (c < NCLASS) ? Wout[k * NCLASS + c] : 0.f;
        }
        if (tid < 256) {
            int c = tid & 127;
            float v = 0.f;
            if (c < NCLASS) v = (tid < 128) ? aout[c] : aout[NCLASS + c];
            apad[tid] = v;
        }
        return;
    }
    __shared__ float xs[64][132];
    int r0 = b * 64;
    int d = tid & 63;
    int rb = (tid >> 6) * 16;
    float acc[NHEADS][16];
#pragma unroll
    for (int h = 0; h < NHEADS; h++)
#pragma unroll
        for (int r = 0; r < 16; r++) acc[h][r] = 0.f;

    const float* Wd = Ws + d;
    for (int ph = 0; ph < 2; ph++) {
        for (int t = tid; t < 64 * 32; t += 256) {
            int r = t >> 5, c4 = t & 31;
            *(float4*)&xs[r][c4 * 4] =
                *(const float4*)(x + (size_t)(r0 + r) * NFEAT + ph * 128 + c4 * 4);
        }
        __syncthreads();
        for (int k4 = 0; k4 < 128; k4 += 4) {
            int kg = ph * 128 + k4;
            float bb[NHEADS][4];
#pragma unroll
            for (int h = 0; h < NHEADS; h++)
#pragma unroll
                for (int kk = 0; kk < 4; kk++)
                    bb[h][kk] = Wd[(size_t)h * NFEAT * NHID + (kg + kk) * NHID];
#pragma unroll
            for (int r = 0; r < 16; r++) {
                float4 a = *(const float4*)&xs[rb + r][k4];
#pragma unroll
                for (int h = 0; h < NHEADS; h++)
                    acc[h][r] += a.x * bb[h][0] + a.y * bb[h][1] +
                                 a.z * bb[h][2] + a.w * bb[h][3];
            }
        }
        __syncthreads();
    }
#pragma unroll
    for (int h = 0; h < NHEADS; h++)
#pragma unroll
        for (int r = 0; r < 16; r++)
            Wh1[(size_t)(r0 + rb + r) * 256 + h * NHID + d] = acc[h][r];
    float asrc[NHEADS], adst[NHEADS];
#pragma unroll
    for (int h = 0; h < NHEADS; h++) {
        asrc[h] = a_heads[h * 2 * NHID + d];
        adst[h] = a_heads[h * 2 * NHID + NHID + d];
    }
#pragma unroll
    for (int h = 0; h < NHEADS; h++) {
#pragma unroll
        for (int r = 0; r < 16; r++) {
            float s = acc[h][r] * asrc[h];
            float dd = acc[h][r] * adst[h];
#pragma unroll
            for (int o = 32; o > 0; o >>= 1) { s += __shfl_xor(s, o); dd += __shfl_xor(dd, o); }
            if (d == 0) {
                fs1[h * N_NODES + r0 + rb + r] = s;
                fd1[h * N_NODES + r0 + rb + r] = dd;
            }
        }
    }
}

// ---------------------------------------------------------------------------
// K3: layer-1 sparse softmax + aggregate + ELU. Block = node, 4 waves.
// Phase 2 now keeps 4 independent gathers in flight per lane.
// ---------------------------------------------------------------------------
__global__ __launch_bounds__(256) void attn_agg1(const int* __restrict__ nbr,
                                                 const int* __restrict__ deg,
                                                 const float* __restrict__ Wh1,
                                                 const float* __restrict__ fs1,
                                                 const float* __restrict__ fd1,
                                                 float* __restrict__ hcat) {
    int i = blockIdx.x;
    int h = threadIdx.x >> 6, lane = threadIdx.x & 63;
    __shared__ float ebuf[NHEADS][CAP + 1];
    __shared__ int nbrs[CAP];
    __shared__ float inv_s[NHEADS];
    __shared__ float part[NHEADS][256];
    int dg = deg[i];
    for (int t = threadIdx.x; t < dg; t += 256) nbrs[t] = nbr[i * CAP + t];
    __syncthreads();
    float fsi = fs1[h * N_NODES + i];
    const float* fdh = fd1 + h * N_NODES;
    float m = -3.4e38f;
    for (int t = lane; t < dg; t += 64) {
        float e = fsi + fdh[nbrs[t]];
        e = e > 0.f ? e : LRALPHA * e;
        ebuf[h][t] = e;
        m = fmaxf(m, e);
    }
#pragma unroll
    for (int o = 32; o > 0; o >>= 1) m = fmaxf(m, __shfl_xor(m, o));
    float s = 0.f;
    for (int t = lane; t < dg; t += 64) {
        float p = __expf(ebuf[h][t] - m);
        ebuf[h][t] = p;
        s += p;
    }
#pragma unroll
    for (int o = 32; o > 0; o >>= 1) s += __shfl_xor(s, o);
    if (lane == 0) inv_s[h] = 1.f / s;
    __syncthreads();
    int w = h;
    int hh = lane >> 4;
    float4 acc = make_float4(0.f, 0.f, 0.f, 0.f);
    int t = w;
    for (; t + 16 <= dg; t += 16) {   // 4 independent gathers in flight
        int j0 = nbrs[t], j1 = nbrs[t + 4], j2 = nbrs[t + 8], j3 = nbrs[t + 12];
        float4 v0 = ((const float4*)(Wh1 + (size_t)j0 * 256))[lane];
        float4 v1 = ((const float4*)(Wh1 + (size_t)j1 * 256))[lane];
        float4 v2 = ((const float4*)(Wh1 + (size_t)j2 * 256))[lane];
        float4 v3 = ((const float4*)(Wh1 + (size_t)j3 * 256))[lane];
        float p0 = ebuf[hh][t], p1 = ebuf[hh][t + 4];
        float p2 = ebuf[hh][t + 8], p3 = ebuf[hh][t + 12];
        acc.x += p0 * v0.x; acc.y += p0 * v0.y; acc.z += p0 * v0.z; acc.w += p0 * v0.w;
        acc.x += p1 * v1.x; acc.y += p1 * v1.y; acc.z += p1 * v1.z; acc.w += p1 * v1.w;
        acc.x += p2 * v2.x; acc.y += p2 * v2.y; acc.z += p2 * v2.z; acc.w += p2 * v2.w;
        acc.x += p3 * v3.x; acc.y += p3 * v3.y; acc.z += p3 * v3.z; acc.w += p3 * v3.w;
    }
    for (; t < dg; t += 4) {
        int j = nbrs[t];
        float4 v = ((const float4*)(Wh1 + (size_t)j * 256))[lane];
        float p = ebuf[hh][t];
        acc.x += p * v.x; acc.y += p * v.y; acc.z += p * v.z; acc.w += p * v.w;
    }
    ((float4*)part[w])[lane] = acc;
    __syncthreads();
    int dim = threadIdx.x;
    float r = part[0][dim] + part[1][dim] + part[2][dim] + part[3][dim];
    r *= inv_s[dim >> 6];
    r = r > 0.f ? r : expm1f(r);
    hcat[(size_t)i * 256 + dim] = r;
}

// ---------------------------------------------------------------------------
// K4: layer-2 GEMM + coef2 butterfly epilogue.
// ---------------------------------------------------------------------------
__global__ __launch_bounds__(256) void gemm2(const float* __restrict__ hcat,
                                             const float* __restrict__ Wpad,
                                             const float* __restrict__ apad,
                                             float* __restrict__ Wh2,
                                             float* __restrict__ fs2,
                                             float* __restrict__ fd2) {
    int r0 = blockIdx.x * 64;
    __shared__ float xs[64][260];
    for (int t = threadIdx.x; t < 64 * 64; t += 256) {
        int r = t >> 6, c4 = t & 63;
        *(float4*)&xs[r][c4 * 4] = *(const float4*)(hcat + (size_t)(r0 + r) * 256 + c4 * 4);
    }
    __syncthreads();
    int lane = threadIdx.x & 63;
    int c0 = lane * 2;
    int rb = (threadIdx.x >> 6) * 16;
    float acc0[16] = {}, acc1[16] = {};
    for (int k4 = 0; k4 < 256; k4 += 4) {
        float2 b0 = *(const float2*)&Wpad[(k4 + 0) * NCPAD + c0];
        float2 b1 = *(const float2*)&Wpad[(k4 + 1) * NCPAD + c0];
        float2 b2 = *(const float2*)&Wpad[(k4 + 2) * NCPAD + c0];
        float2 b3 = *(const float2*)&Wpad[(k4 + 3) * NCPAD + c0];
#pragma unroll
        for (int r = 0; r < 16; r++) {
            float4 a = *(const float4*)&xs[rb + r][k4];
            acc0[r] += a.x * b0.x + a.y * b1.x + a.z * b2.x + a.w * b3.x;
            acc1[r] += a.x * b0.y + a.y * b1.y + a.z * b2.y + a.w * b3.y;
        }
    }
#pragma unroll
    for (int r = 0; r < 16; r++)
        *(float2*)&Wh2[(size_t)(r0 + rb + r) * NCPAD + c0] = make_float2(acc0[r], acc1[r]);
    float as0 = apad[c0], as1 = apad[c0 + 1];
    float ad0 = apad[128 + c0], ad1 = apad[128 + c0 + 1];
#pragma unroll
    for (int r = 0; r < 16; r++) {
        float s = acc0[r] * as0 + acc1[r] * as1;
        float dd = acc0[r] * ad0 + acc1[r] * ad1;
#pragma unroll
        for (int o = 32; o > 0; o >>= 1) { s += __shfl_xor(s, o); dd += __shfl_xor(dd, o); }
        if (lane == 0) { fs2[r0 + rb + r] = s; fd2[r0 + rb + r] = dd; }
    }
}

// ---------------------------------------------------------------------------
// K5: layer-2 sparse softmax + aggregate. Block = node, 4 waves (256 thr).
// Phase 2: 4 independent float2 gathers in flight.
// ---------------------------------------------------------------------------
__global__ __launch_bounds__(256) void attn_agg2(const int* __restrict__ nbr,
                                                 const int* __restrict__ deg,
                                                 const float* __restrict__ Wh2,
                                                 const float* __restrict__ fs2,
                                                 const float* __restrict__ fd2,
                                                 float* __restrict__ out) {
    int i = blockIdx.x;
    int w = threadIdx.x >> 6, lane = threadIdx.x & 63;
    __shared__ float ebuf[CAP];
    __shared__ int nbrs[CAP];
    __shared__ float red[4];
    __shared__ float part[4][128];
    __shared__ float inv_s;
    int dg = deg[i];
    for (int t = threadIdx.x; t < dg; t += 256) nbrs[t] = nbr[i * CAP + t];
    __syncthreads();
    float fsi = fs2[i];
    float m = -3.4e38f;
    for (int t = threadIdx.x; t < dg; t += 256) {
        float e = fsi + fd2[nbrs[t]];
        e = e > 0.f ? e : LRALPHA * e;
        ebuf[t] = e;
        m = fmaxf(m, e);
    }
#pragma unroll
    for (int o = 32; o > 0; o >>= 1) m = fmaxf(m, __shfl_xor(m, o));
    if (lane == 0) red[w] = m;
    __syncthreads();
    m = fmaxf(fmaxf(red[0], red[1]), fmaxf(red[2], red[3]));
    float s = 0.f;
    for (int t = threadIdx.x; t < dg; t += 256) {
        float p = __expf(ebuf[t] - m);
        ebuf[t] = p;
        s += p;
    }
#pragma unroll
    for (int o = 32; o > 0; o >>= 1) s += __shfl_xor(s, o);
    __syncthreads();
    if (lane == 0) red[w] = s;
    __syncthreads();
    if (threadIdx.x == 0) inv_s = 1.f / (red[0] + red[1] + red[2] + red[3]);
    __syncthreads();
    float2 acc = make_float2(0.f, 0.f);
    int t = w;
    for (; t + 16 <= dg; t += 16) {
        int j0 = nbrs[t], j1 = nbrs[t + 4], j2 = nbrs[t + 8], j3 = nbrs[t + 12];
        float2 v0 = ((const float2*)(Wh2 + (size_t)j0 * NCPAD))[lane];
        float2 v1 = ((const float2*)(Wh2 + (size_t)j1 * NCPAD))[lane];
        float2 v2 = ((const float2*)(Wh2 + (size_t)j2 * NCPAD))[lane];
        float2 v3 = ((const float2*)(Wh2 + (size_t)j3 * NCPAD))[lane];
        float p0 = ebuf[t], p1 = ebuf[t + 4], p2 = ebuf[t + 8], p3 = ebuf[t + 12];
        acc.x += p0 * v0.x; acc.y += p0 * v0.y;
        acc.x += p1 * v1.x; acc.y += p1 * v1.y;
        acc.x += p2 * v2.x; acc.y += p2 * v2.y;
        acc.x += p3 * v3.x; acc.y += p3 * v3.y;
    }
    for (; t < dg; t += 4) {
        int j = nbrs[t];
        float2 v = ((const float2*)(Wh2 + (size_t)j * NCPAD))[lane];
        float p = ebuf[t];
        acc.x += p * v.x; acc.y += p * v.y;
    }
    ((float2*)part[w])[lane] = acc;
    __syncthreads();
    if (threadIdx.x < NCPAD) {
        int dim = threadIdx.x;
        float r = (part[0][dim] + part[1][dim] + part[2][dim] + part[3][dim]) * inv_s;
        if (dim < NCLASS) out[(size_t)i * NCLASS + dim] = r;
    }
}

// ---------------------------------------------------------------------------

extern "C" void kernel_launch(void* const* d_in, const int* in_sizes, int n_in,
                              void* d_out, int out_size, void* d_ws, size_t ws_size,
                              hipStream_t stream) {
    const float* x       = (const float*)d_in[0];  // [8192,256]
    const float* adj     = (const float*)d_in[1];  // [8192,8192]
    const float* Ws      = (const float*)d_in[2];  // [4,256,64]
    const float* a_heads = (const float*)d_in[3];  // [4,128]
    const float* Wout    = (const float*)d_in[4];  // [256,121]
    const float* aout    = (const float*)d_in[5];  // [242]
    float* out = (float*)d_out;                    // [8192,121]

    char* ws = (char*)d_ws;
    size_t off = 0;
    auto alloc = [&](size_t bytes) { void* p = ws + off; off = (off + bytes + 255) & ~(size_t)255; return p; };
    int*   nbr  = (int*)  alloc((size_t)N_NODES * CAP * 4);
    int*   deg  = (int*)  alloc((size_t)N_NODES * 4);
    float* Wh1  = (float*)alloc((size_t)N_NODES * NHEADS * NHID * 4);
    float* fs1  = (float*)alloc((size_t)NHEADS * N_NODES * 4);
    float* fd1  = (float*)alloc((size_t)NHEADS * N_NODES * 4);
    float* hcat = (float*)alloc((size_t)N_NODES * NHEADS * NHID * 4);
    float* Wh2  = (float*)alloc((size_t)N_NODES * NCPAD * 4);
    float* fs2  = (float*)alloc((size_t)N_NODES * 4);
    float* fd2  = (float*)alloc((size_t)N_NODES * 4);
    float* Wpad = (float*)alloc((size_t)256 * NCPAD * 4);
    float* apad = (float*)alloc((size_t)256 * 4);

    build_csr<<<N_NODES, 256, 0, stream>>>(adj, nbr, deg);
    gemm1<<<N_NODES / 64 + 1, 256, 0, stream>>>(x, Ws, a_heads, Wout, aout,
                                                Wh1, fs1, fd1, Wpad, apad);
    attn_agg1<<<N_NODES, 256, 0, stream>>>(nbr, deg, Wh1, fs1, fd1, hcat);
    gemm2<<<N_NODES / 64, 256, 0, stream>>>(hcat, Wpad, apad, Wh2, fs2, fd2);
    attn_agg2<<<N_NODES, 256, 0, stream>>>(nbr, deg, Wh2, fs2, fd2, out);
}